// Round 8
// baseline (621.245 us; speedup 1.0000x reference)
//
#include <hip/hip_runtime.h>
#include <hip/hip_bf16.h>
#include <cstdint>
#include <cstddef>

#define T_STEPS 8192
#define D_OBS 256
#define D_ACT 16
#define D_MLP 1024
#define D_REC 1024
#define G3REC 3072
#define K_MAX 20          // wavefront iterations 0..K_MAX-1; cleanup handles len > K_MAX
#define HCAP 4608         // Hf32 row capacity (nseg ~ 4096 +/- 45; 11-sigma headroom)

typedef short bf16x8_t __attribute__((ext_vector_type(8)));
typedef float f32x4_t __attribute__((ext_vector_type(4)));

__device__ __forceinline__ float b2f(unsigned short u) {
  union { uint32_t i; float f; } v; v.i = ((uint32_t)u) << 16; return v.f;
}
__device__ __forceinline__ unsigned short f2b(float f) {
  union { float f; uint32_t i; } v; v.f = f;
  uint32_t r = v.i + 0x7fffu + ((v.i >> 16) & 1u);
  return (unsigned short)(r >> 16);
}
__device__ __forceinline__ float mishf(float v) {
  float sp = (v > 15.f) ? v : log1pf(expf(v));
  return v * tanhf(sp);
}
__device__ __forceinline__ float sigmf(float x) { return 1.f / (1.f + expf(-x)); }

// async global->LDS, 16B per lane; LDS dest = wave-uniform base + lane*16.
__device__ __forceinline__ void gload_lds16(const void* g, void* l) {
  __builtin_amdgcn_global_load_lds((const __attribute__((address_space(1))) void*)g,
                                   (__attribute__((address_space(3))) void*)l, 16, 0, 0);
}

// LDS swizzle (bank-conflict fix, both-sides rule #21), BK=32 tiles:
// [R][32]el bf16 tile as R*4 slots of 16B. slot s holds data chunk
// (row = s>>2, j = (s&3) ^ ((s>>3)&3)). Reads for (row,j) use
// slot row*4 + (j ^ ((row>>1)&3)). 16 rows/same-j -> 2 lanes/bank (free).
__device__ __forceinline__ int swz_src_j(int slot) {   // source chunk j for linear slot
  return (slot & 3) ^ ((slot >> 3) & 3);
}
__device__ __forceinline__ int swz_read_off(int row, int j) {  // element offset in tile
  return row * 32 + ((j ^ ((row >> 1) & 3)) << 3);
}

// ---- f32 -> bf16 conversion ----
__global__ __launch_bounds__(256) void cvt_f32_bf16(
    const float* __restrict__ in, unsigned short* __restrict__ out, int n4) {
  int stride = gridDim.x * blockDim.x;
  for (int j = blockIdx.x * blockDim.x + threadIdx.x; j < n4; j += stride) {
    float4 v = ((const float4*)in)[j];
    ushort4 o;
    o.x = f2b(v.x); o.y = f2b(v.y); o.z = f2b(v.z); o.w = f2b(v.w);
    ((ushort4*)out)[j] = o;
  }
}

// w_hh [3072,1024] f32 -> w_perm bf16 with row permutation: out row 3u+g = in row g*1024+u.
__global__ __launch_bounds__(256) void cvt_whh_perm(
    const float* __restrict__ in, unsigned short* __restrict__ out) {
  int r = blockIdx.x;                 // original row
  int g = r >> 10, u = r & 1023;
  unsigned short* dst = out + (size_t)(u * 3 + g) * D_REC;
  const float* src = in + (size_t)r * D_REC;
  for (int c = threadIdx.x * 4; c < D_REC; c += 1024) {
    float4 v = *(const float4*)&src[c];
    ushort4 o; o.x = f2b(v.x); o.y = f2b(v.y); o.z = f2b(v.z); o.w = f2b(v.w);
    *(ushort4*)&dst[c] = o;
  }
}

// C[M,N] = act(A[M,K] @ B[N,K]^T + bias[N]); A,B,C bf16, bias f32, f32 accum.
// Block tile (MT*32) x (NT*32), BK=32, 4 waves (2x2), each wave (MT*16)x(NT*16),
// dbuf global_load_lds staging + swizzled LDS (2-way max bank alias).
template <int ACT, int MT, int NT>
__global__ __launch_bounds__(256) void gemm_tn(
    const unsigned short* __restrict__ A,
    const unsigned short* __restrict__ B,
    const float* __restrict__ bias,
    unsigned short* __restrict__ C,
    int M, int N, int K) {
  constexpr int BM = MT * 32, BN = NT * 32;
  constexpr int CA = BM / 64, CB = BN / 64;   // staging chunks per thread
  __shared__ unsigned short lds_a[2][BM * 32];
  __shared__ unsigned short lds_b[2][BN * 32];
  const int tid = threadIdx.x;
  const int lane = tid & 63;
  const int wave = tid >> 6;
  const int wr = wave >> 1, wc = wave & 1;
  const int row0 = blockIdx.x * BM, col0 = blockIdx.y * BN;
  f32x4_t acc[MT][NT] = {};
  const int lrow = lane & 15, j = lane >> 4;
  // staging sources: chunk p -> slot = p*256 + tid, row = slot>>2, swizzled col
  const unsigned short* srcA[CA];
  const unsigned short* srcB[CB];
#pragma unroll
  for (int p = 0; p < CA; ++p) {
    int slot = p * 256 + tid;
    srcA[p] = &A[(size_t)(row0 + (slot >> 2)) * K + swz_src_j(slot) * 8];
  }
#pragma unroll
  for (int p = 0; p < CB; ++p) {
    int slot = p * 256 + tid;
    srcB[p] = &B[(size_t)(col0 + (slot >> 2)) * K + swz_src_j(slot) * 8];
  }
  const int so = wave * 512;  // per-wave lane-linear LDS base (elements)
  auto stage = [&](int buf, int k0) {
#pragma unroll
    for (int p = 0; p < CA; ++p)
      gload_lds16(srcA[p] + k0, &lds_a[buf][p * 2048 + so]);
#pragma unroll
    for (int p = 0; p < CB; ++p)
      gload_lds16(srcB[p] + k0, &lds_b[buf][p * 2048 + so]);
  };
  // precompute swizzled read offsets (K-invariant)
  int aoff[MT], boff[NT];
#pragma unroll
  for (int m = 0; m < MT; ++m)
    aoff[m] = swz_read_off(wr * (MT * 16) + m * 16 + lrow, j);
#pragma unroll
  for (int n = 0; n < NT; ++n)
    boff[n] = swz_read_off(wc * (NT * 16) + n * 16 + lrow, j);
  const int nk = K >> 5;
  stage(0, 0);
  __syncthreads();
  int cur = 0;
  for (int t = 0; t < nk; ++t) {
    if (t + 1 < nk) stage(cur ^ 1, (t + 1) << 5);
    bf16x8_t af[MT], bfr[NT];
#pragma unroll
    for (int m = 0; m < MT; ++m)
      af[m] = *(const bf16x8_t*)&lds_a[cur][aoff[m]];
#pragma unroll
    for (int n = 0; n < NT; ++n)
      bfr[n] = *(const bf16x8_t*)&lds_b[cur][boff[n]];
#pragma unroll
    for (int m = 0; m < MT; ++m)
#pragma unroll
      for (int n = 0; n < NT; ++n)
        acc[m][n] = __builtin_amdgcn_mfma_f32_16x16x32_bf16(af[m], bfr[n], acc[m][n], 0, 0, 0);
    __syncthreads();   // drains vmcnt(0): next buf staged; lgkm: cur reads done
    cur ^= 1;
  }
  // C/D layout (verified m89/m91): col = lane&15, row = (lane>>4)*4 + jj
#pragma unroll
  for (int n = 0; n < NT; ++n) {
    int col = col0 + wc * (NT * 16) + n * 16 + lrow;
    float bv = bias[col];
#pragma unroll
    for (int m = 0; m < MT; ++m) {
#pragma unroll
      for (int jj = 0; jj < 4; ++jj) {
        int row = row0 + wr * (MT * 16) + m * 16 + j * 4 + jj;
        float v = acc[m][n][jj] + bv;
        if (ACT) v = mishf(v);
        C[(size_t)row * N + col] = f2b(v);
      }
    }
  }
}

// ---- start-flag dtype detection (int32 vs uint8) + nseg zeroing ----
__global__ void detect_start_mode(const unsigned int* __restrict__ w,
                                  int* __restrict__ mode, int* __restrict__ nseg) {
  if (threadIdx.x == 0 && blockIdx.x == 0) {
    int m = 0;
    for (int i = 0; i < 64; ++i)
      if (w[i] > 1u) m = 1;
    *mode = m;  // 1 = uint8, 0 = int32
    *nseg = 0;
  }
}
__device__ __forceinline__ int start_flag(const void* start, int mode, int t) {
  if (mode) return ((const unsigned char*)start)[t] != 0;
  return ((const int*)start)[t] != 0;
}

// ---- segment list: every t with (t==0 || start[t]) begins a segment ----
__global__ __launch_bounds__(256) void seg_build(
    const void* __restrict__ start, const int* __restrict__ mode_p,
    int* __restrict__ t0_raw, int* __restrict__ len_raw, int* __restrict__ nseg) {
  int t = blockIdx.x * blockDim.x + threadIdx.x;
  if (t >= T_STEPS) return;
  int mode = *mode_p;
  if (t != 0 && !start_flag(start, mode, t)) return;
  int len = 1;
  while (t + len < T_STEPS && !start_flag(start, mode, t + len)) ++len;
  int slot = atomicAdd(nseg, 1);
  t0_raw[slot] = t;
  len_raw[slot] = len;
}

// ---- counting sort by length (descending); counts[i] = #segments with len > i ----
__global__ __launch_bounds__(256) void seg_sort(
    const int* __restrict__ t0_raw, const int* __restrict__ len_raw,
    const int* __restrict__ nseg_p,
    int* __restrict__ t0s, int* __restrict__ len_s, int* __restrict__ counts) {
  __shared__ int hist[K_MAX + 2], off[K_MAX + 2];
  int tid = threadIdx.x;
  int n = *nseg_p;
  if (tid < K_MAX + 2) hist[tid] = 0;
  __syncthreads();
  for (int s = tid; s < n; s += 256)
    atomicAdd(&hist[min(len_raw[s], K_MAX + 1)], 1);
  __syncthreads();
  if (tid == 0) {
    int acc = 0;
    for (int b = K_MAX + 1; b >= 1; --b) { off[b] = acc; acc += hist[b]; }
    for (int i = 0; i <= K_MAX; ++i) {
      int c = 0;
      for (int b = i + 1; b <= K_MAX + 1; ++b) c += hist[b];
      counts[i] = c;
    }
  }
  __syncthreads();
  for (int s = tid; s < n; s += 256) {
    int pos = atomicAdd(&off[min(len_raw[s], K_MAX + 1)], 1);
    t0s[pos] = t0_raw[s];
    len_s[pos] = len_raw[s];
  }
}

// ---- hg0 = w_hh(f32) @ state0(f32): only segment containing t=0 needs a nonzero h ----
__global__ __launch_bounds__(256) void matvec0(
    const float* __restrict__ w_hh, const float* __restrict__ state0,
    float* __restrict__ hg0) {
  int g = threadIdx.x >> 4, l16 = threadIdx.x & 15;
  int row = blockIdx.x * 16 + g;
  const float* wr = w_hh + (size_t)row * D_REC;
  float s = 0.f;
#pragma unroll
  for (int i = 0; i < 16; ++i) {
    int c = (l16 + i * 16) * 4;
    float4 w4 = *(const float4*)&wr[c];
    float4 h4 = *(const float4*)&state0[c];
    s += w4.x * h4.x + w4.y * h4.y + w4.z * h4.z + w4.w * h4.w;
  }
#pragma unroll
  for (int o = 1; o < 16; o <<= 1) s += __shfl_xor(s, o);
  if (l16 == 0) hg0[row] = s;
}

// ---- iteration 0 gate: h_prev = state0 (seg at t=0, no reset) or 0 ----
__global__ __launch_bounds__(256) void gru_gate0(
    unsigned short* __restrict__ states, const unsigned short* __restrict__ igates,
    const void* __restrict__ start, const int* __restrict__ mode_p,
    const int* __restrict__ t0s, const int* __restrict__ nseg_p,
    const float* __restrict__ hg0, const float* __restrict__ state0,
    const float* __restrict__ b_n, float* __restrict__ Hf32,
    float* __restrict__ finals) {
  int p = blockIdx.x;
  if (p >= *nseg_p) return;
  int t0 = t0s[p];
  int mode = *mode_p;
  bool use_s0 = (t0 == 0) && !start_flag(start, mode, 0);
  size_t ib = (size_t)t0 * G3REC;
  for (int u = threadIdx.x; u < D_REC; u += 256) {
    float hp = use_s0 ? state0[u] : 0.f;
    float hr = use_s0 ? hg0[u] : 0.f;
    float hz = use_s0 ? hg0[D_REC + u] : 0.f;
    float hn = use_s0 ? hg0[2 * D_REC + u] : 0.f;
    float r = sigmf(b2f(igates[ib + u]) + hr);
    float z = sigmf(b2f(igates[ib + D_REC + u]) + hz);
    float n = tanhf(b2f(igates[ib + 2 * D_REC + u]) + r * (hn + b_n[u]));
    float hnew = n + z * (hp - n);
    if (p < HCAP) Hf32[(size_t)p * D_REC + u] = hnew;
    states[(size_t)t0 * D_REC + u] = f2b(hnew);
    if (t0 == T_STEPS - 1) finals[u] = hnew;
  }
}

// ---- fused wavefront iteration i>=1 (barrier-free K-loop version).
// Tile: 128 segments x 96 w_perm-rows (=32 units x 3 gates). 4 waves.
// B (96 rows) fully LDS-resident per K-half (96 KB, swizzled c' = c ^ (row&7));
// A per-lane direct global->reg (no barriers in K-loop -> compiler pipelines);
// epilogue inputs (igates x3, Hf32, t) prefetched at kernel entry (T14).
__global__ __launch_bounds__(256) void gru_iter(
    unsigned short* __restrict__ states,
    const unsigned short* __restrict__ igates,
    const unsigned short* __restrict__ w_perm,
    const int* __restrict__ t0s, const int* __restrict__ counts,
    const float* __restrict__ b_n, float* __restrict__ Hf32,
    float* __restrict__ finals, int iter) {
  const int count = counts[iter];
  const int row0 = blockIdx.x * 128;
  if (row0 >= count) return;
  const int u0 = blockIdx.y * 32;
  const int col0 = u0 * 3;
  __shared__ __align__(16) unsigned short lds_b[96 * 512];  // 96 KB (one K-half)
  float* hgl = (float*)lds_b;                               // [128][98] f32, aliased after
  const int tid = threadIdx.x;
  const int lane = tid & 63, wave = tid >> 6;
  const int lrow = lane & 15, j = lane >> 4;

  // ---- epilogue prefetch: 16 (seg,unit) pairs per thread ----
  unsigned short pg0[16], pg1[16], pg2[16];
  float php[16];
  int pt[16];
#pragma unroll
  for (int k = 0; k < 16; ++k) {
    int idx = k * 256 + tid;
    int pl = idx >> 5, ul = idx & 31;
    int p = row0 + pl;
    int pc = (p < count) ? p : 0;
    int t = t0s[pc] + iter;
    pt[k] = t;
    int u = u0 + ul;
    size_t ib = (size_t)t * G3REC;
    pg0[k] = igates[ib + u];
    pg1[k] = igates[ib + D_REC + u];
    pg2[k] = igates[ib + 2 * D_REC + u];
    php[k] = Hf32[(size_t)pc * D_REC + u];
  }
  // ---- per-lane A row base addresses (2 fragment rows per lane) ----
  const unsigned short* arow[2];
#pragma unroll
  for (int m = 0; m < 2; ++m) {
    int p = row0 + wave * 32 + m * 16 + lrow;
    int pc = (p < count) ? p : 0;
    arow[m] = states + (size_t)(t0s[pc] + iter - 1) * D_REC;
  }

  f32x4_t acc[2][6] = {};
  for (int half = 0; half < 2; ++half) {
    __syncthreads();   // protect lds_b from prior-half readers (no-op at half 0)
    // stage B half: rows col0..+95, cols half*512..+512; swizzle c'=(c&56)|((c^row)&7)
#pragma unroll
    for (int s = 0; s < 24; ++s) {
      int slot = s * 256 + tid;           // 6144 slots of 16B
      int br = slot >> 6;                 // 0..95
      int cq = slot & 63;                 // dest chunk
      int csrc = (cq & 56) | ((cq ^ br) & 7);
      gload_lds16(w_perm + (size_t)(col0 + br) * D_REC + half * 512 + csrc * 8,
                  lds_b + (size_t)(s * 256 + wave * 64) * 8);
    }
    __syncthreads();   // B half ready (drains vmcnt)
    const int kbase = half * 512;
#pragma unroll
    for (int kk = 0; kk < 16; ++kk) {     // 16 K-steps of 32, NO barriers
      const int k0 = kk * 32;
      bf16x8_t af[2];
#pragma unroll
      for (int m = 0; m < 2; ++m)
        af[m] = *(const bf16x8_t*)(arow[m] + kbase + k0 + j * 8);
      bf16x8_t bfr[6];
#pragma unroll
      for (int n = 0; n < 6; ++n) {
        int brow = n * 16 + lrow;
        int c = (k0 >> 3) + j;
        int cq = (c & 56) | ((c ^ brow) & 7);
        bfr[n] = *(const bf16x8_t*)&lds_b[brow * 512 + cq * 8];
      }
#pragma unroll
      for (int m = 0; m < 2; ++m)
#pragma unroll
        for (int n = 0; n < 6; ++n)
          acc[m][n] = __builtin_amdgcn_mfma_f32_16x16x32_bf16(af[m], bfr[n], acc[m][n], 0, 0, 0);
    }
  }
  __syncthreads();   // all B reads done; lds_b now reused as hgl
  // dump acc tile (row-local x 96 cols, stride 98 to dodge bank conflicts)
#pragma unroll
  for (int m = 0; m < 2; ++m)
#pragma unroll
    for (int n = 0; n < 6; ++n)
#pragma unroll
      for (int jj = 0; jj < 4; ++jj) {
        int row = wave * 32 + m * 16 + j * 4 + jj;
        hgl[row * 98 + n * 16 + lrow] = acc[m][n][jj];
      }
  __syncthreads();
  // gate epilogue from prefetched inputs
#pragma unroll
  for (int k = 0; k < 16; ++k) {
    int idx = k * 256 + tid;
    int pl = idx >> 5, ul = idx & 31;
    int p = row0 + pl;
    if (p >= count) continue;
    int t = pt[k];
    int u = u0 + ul;
    float hr = hgl[pl * 98 + 3 * ul + 0];
    float hz = hgl[pl * 98 + 3 * ul + 1];
    float hn = hgl[pl * 98 + 3 * ul + 2];
    float r = sigmf(b2f(pg0[k]) + hr);
    float z = sigmf(b2f(pg1[k]) + hz);
    float n = tanhf(b2f(pg2[k]) + r * (hn + b_n[u]));
    float hnew = n + z * (php[k] - n);
    Hf32[(size_t)p * D_REC + u] = hnew;
    states[(size_t)t * D_REC + u] = f2b(hnew);
    if (t == T_STEPS - 1) finals[u] = hnew;
  }
}

// ---- sequential tail for segments with len > K_MAX (w.h.p. none) ----
__global__ __launch_bounds__(256) void gru_cleanup(
    unsigned short* __restrict__ states, const unsigned short* __restrict__ igates,
    const unsigned short* __restrict__ w_perm,
    const int* __restrict__ t0s, const int* __restrict__ len_s,
    const int* __restrict__ counts, const float* __restrict__ b_n,
    const float* __restrict__ Hf32, float* __restrict__ finals) {
  int p = blockIdx.x;
  if (p >= counts[K_MAX]) return;  // segments with len > K_MAX (sorted first)
  int t0 = t0s[p], len = len_s[p];
  __shared__ float h[D_REC];
  __shared__ float hgl[G3REC];
  const int tid = threadIdx.x;
  for (int u = tid; u < D_REC; u += 256) h[u] = Hf32[(size_t)p * D_REC + u];
  __syncthreads();
  const int g = tid >> 4, l16 = tid & 15;
  for (int s = K_MAX; s < len; ++s) {
    int t = t0 + s;
    float hreg[64];
#pragma unroll
    for (int i = 0; i < 8; ++i) {
      float4 a = *(const float4*)&h[l16 * 8 + i * 128];
      float4 b = *(const float4*)&h[l16 * 8 + i * 128 + 4];
      hreg[i * 8 + 0] = a.x; hreg[i * 8 + 1] = a.y; hreg[i * 8 + 2] = a.z; hreg[i * 8 + 3] = a.w;
      hreg[i * 8 + 4] = b.x; hreg[i * 8 + 5] = b.y; hreg[i * 8 + 6] = b.z; hreg[i * 8 + 7] = b.w;
    }
    for (int row = g; row < G3REC; row += 16) {
      const unsigned short* wrow = w_perm + (size_t)row * D_REC;
      float sum = 0.f;
#pragma unroll
      for (int i = 0; i < 8; ++i) {
        bf16x8_t wv = *(const bf16x8_t*)&wrow[l16 * 8 + i * 128];
#pragma unroll
        for (int jj = 0; jj < 8; ++jj)
          sum += b2f((unsigned short)wv[jj]) * hreg[i * 8 + jj];
      }
#pragma unroll
      for (int o = 1; o < 16; o <<= 1) sum += __shfl_xor(sum, o);
      if (l16 == 0) hgl[row] = sum;
    }
    __syncthreads();
    size_t ib = (size_t)t * G3REC;
    for (int u = tid; u < D_REC; u += 256) {
      float r = sigmf(b2f(igates[ib + u]) + hgl[3 * u + 0]);
      float z = sigmf(b2f(igates[ib + D_REC + u]) + hgl[3 * u + 1]);
      float n = tanhf(b2f(igates[ib + 2 * D_REC + u]) + r * (hgl[3 * u + 2] + b_n[u]));
      float hnew = n + z * (h[u] - n);
      h[u] = hnew;
      states[(size_t)t * D_REC + u] = f2b(hnew);
      if (t == T_STEPS - 1) finals[u] = hnew;
    }
    __syncthreads();
  }
}

// ---- heads + dueling epilogue (one wave per timestep) ----
__global__ __launch_bounds__(64) void heads_kernel(
    const unsigned short* __restrict__ y,
    const float* __restrict__ Wv, const float* __restrict__ bv,
    const float* __restrict__ Wa, const float* __restrict__ ba,
    const float* __restrict__ Ws, const float* __restrict__ bs,
    float* __restrict__ q) {
  const int t = blockIdx.x, lane = threadIdx.x;
  const unsigned short* yr = y + (size_t)t * D_MLP;
  float yv[16];
#pragma unroll
  for (int c = 0; c < 2; ++c) {
    bf16x8_t v = *(const bf16x8_t*)&yr[lane * 16 + c * 8];
#pragma unroll
    for (int j = 0; j < 8; ++j) yv[c * 8 + j] = b2f((unsigned short)v[j]);
  }
  float mine = 0.f;
  for (int o = 0; o < 18; ++o) {
    const float* w = (o < 16) ? (Wa + (size_t)o * D_MLP) : (o == 16 ? Wv : Ws);
    float s = 0.f;
#pragma unroll
    for (int c = 0; c < 4; ++c) {
      float4 wv = *(const float4*)&w[lane * 16 + c * 4];
      s += wv.x * yv[c * 4 + 0] + wv.y * yv[c * 4 + 1] +
           wv.z * yv[c * 4 + 2] + wv.w * yv[c * 4 + 3];
    }
#pragma unroll
    for (int off = 1; off < 64; off <<= 1) s += __shfl_xor(s, off);
    if (lane == o) mine = s;
  }
  if (lane < 16) mine += ba[lane];
  else if (lane == 16) mine += bv[0];
  else if (lane == 17) mine += bs[0];
  float a = (lane < 16) ? mine : 0.f;
  float ss = a * a;
#pragma unroll
  for (int off = 1; off < 64; off <<= 1) ss += __shfl_xor(ss, off);
  float an = a / (1e-6f + sqrtf(ss));
  float ms = (lane < 16) ? an : 0.f;
#pragma unroll
  for (int off = 1; off < 64; off <<= 1) ms += __shfl_xor(ms, off);
  float adv = an - ms * (1.f / 16.f);
  float val = __shfl(mine, 16);
  float sc = __shfl(mine, 17);
  if (lane < 16) q[(size_t)t * D_ACT + lane] = val + sc * adv;
}

extern "C" void kernel_launch(void* const* d_in, const int* in_sizes, int n_in,
                              void* d_out, int out_size, void* d_ws, size_t ws_size,
                              hipStream_t stream) {
  const float* x      = (const float*)d_in[0];
  const float* state0 = (const float*)d_in[1];
  const void*  start  = d_in[2];
  const float* W_pre  = (const float*)d_in[3];
  const float* b_pre  = (const float*)d_in[4];
  const float* w_ih   = (const float*)d_in[5];
  const float* w_hh   = (const float*)d_in[6];
  const float* b_ih   = (const float*)d_in[7];
  const float* b_n    = (const float*)d_in[8];
  const float* W1     = (const float*)d_in[9];
  const float* b1     = (const float*)d_in[10];
  const float* W2     = (const float*)d_in[11];
  const float* b2     = (const float*)d_in[12];
  const float* Wv     = (const float*)d_in[13];
  const float* bv     = (const float*)d_in[14];
  const float* Wa     = (const float*)d_in[15];
  const float* ba     = (const float*)d_in[16];
  const float* Ws     = (const float*)d_in[17];
  const float* bs     = (const float*)d_in[18];

  // workspace layout (phases: A=pre/igates, B=scan, C=post). Peak < 99 MB.
  char* ws = (char*)d_ws;
  const size_t MB = 1ull << 20;
  unsigned short* igates = (unsigned short*)(ws);
  unsigned short* y2     = igates;
  unsigned short* xp     = (unsigned short*)(ws + 48 * MB);
  float*          Hf32   = (float*)(ws + 48 * MB);
  unsigned short* y1     = xp;
  unsigned short* states = (unsigned short*)(ws + 66 * MB);
  unsigned short* x_bf   = (unsigned short*)(ws + 82 * MB);
  unsigned short* w_perm = (unsigned short*)(ws + 82 * MB);
  unsigned short* Wpre_bf= (unsigned short*)(ws + 88 * MB);
  unsigned short* wih_bf = (unsigned short*)(ws + 88 * MB + 512 * 1024);
  unsigned short* W1_bf  = (unsigned short*)(ws + 94 * MB + 512 * 1024);
  unsigned short* W2_bf  = (unsigned short*)(ws + 96 * MB + 512 * 1024);
  char* seg = ws + 98 * MB + 512 * 1024;
  int* t0_raw  = (int*)(seg);
  int* len_raw = (int*)(seg + 32768);
  int* t0s     = (int*)(seg + 65536);
  int* len_s   = (int*)(seg + 98304);
  int* counts  = (int*)(seg + 131072);
  int* nseg_p  = (int*)(seg + 131072 + 128);
  int* mode_p  = (int*)(seg + 131072 + 192);
  float* hg0   = (float*)(seg + 131072 + 256);
  float* qout   = (float*)d_out;
  float* finals = qout + (size_t)T_STEPS * D_ACT;

  detect_start_mode<<<1, 64, 0, stream>>>((const unsigned int*)start, mode_p, nseg_p);
  cvt_f32_bf16<<<512, 256, 0, stream>>>(x,     x_bf,    (T_STEPS * D_OBS) / 4);
  cvt_f32_bf16<<<256, 256, 0, stream>>>(W_pre, Wpre_bf, (D_MLP * D_OBS) / 4);
  cvt_f32_bf16<<<768, 256, 0, stream>>>(w_ih,  wih_bf,  (G3REC * D_MLP) / 4);
  cvt_f32_bf16<<<512, 256, 0, stream>>>(W1,    W1_bf,   (D_MLP * D_REC) / 4);
  cvt_f32_bf16<<<512, 256, 0, stream>>>(W2,    W2_bf,   (D_MLP * D_MLP) / 4);
  seg_build<<<32, 256, 0, stream>>>(start, mode_p, t0_raw, len_raw, nseg_p);
  seg_sort<<<1, 256, 0, stream>>>(t0_raw, len_raw, nseg_p, t0s, len_s, counts);
  matvec0<<<192, 256, 0, stream>>>(w_hh, state0, hg0);

  // pre-MLP (64^2 tile), then w_hh permute-convert, then igates GEMM (128^2 tile)
  gemm_tn<1, 2, 2><<<dim3(128, 16), 256, 0, stream>>>(x_bf, Wpre_bf, b_pre, xp, T_STEPS, D_MLP, D_OBS);
  cvt_whh_perm<<<3072, 256, 0, stream>>>(w_hh, w_perm);
  gemm_tn<0, 4, 4><<<dim3(64, 24), 256, 0, stream>>>(xp, wih_bf, b_ih, igates, T_STEPS, G3REC, D_MLP);

  // wavefront scan
  gru_gate0<<<8192, 256, 0, stream>>>(states, igates, start, mode_p, t0s, nseg_p,
                                      hg0, state0, b_n, Hf32, finals);
  for (int i = 1; i < K_MAX; ++i) {
    int mt = (8192 / (i + 1) + 127) / 128;  // count_i <= 8192/(i+1)
    gru_iter<<<dim3(mt, 32), 256, 0, stream>>>(states, igates, w_perm, t0s, counts,
                                               b_n, Hf32, finals, i);
  }
  gru_cleanup<<<512, 256, 0, stream>>>(states, igates, w_perm, t0s, len_s, counts,
                                       b_n, Hf32, finals);

  // post MLP (64^2 tiles) + heads
  gemm_tn<1, 2, 2><<<dim3(128, 16), 256, 0, stream>>>(states, W1_bf, b1, y1, T_STEPS, D_MLP, D_REC);
  gemm_tn<1, 2, 2><<<dim3(128, 16), 256, 0, stream>>>(y1, W2_bf, b2, y2, T_STEPS, D_MLP, D_MLP);
  heads_kernel<<<8192, 64, 0, stream>>>(y2, Wv, bv, Wa, ba, Ws, bs, qout);
}